// Round 7
// baseline (19512.352 us; speedup 1.0000x reference)
//
#include <hip/hip_runtime.h>

#define SEQ   256
#define DIN   8192
#define BATCH 2048
#define HID   512
#define G4    2048   // 4*HID
#define KG    544    // HID + 32
#define NBLK  256

typedef __attribute__((ext_vector_type(8))) short short8;
typedef __attribute__((ext_vector_type(4))) float f32x4;

static __device__ __forceinline__ unsigned short f2bf(float f) {
  unsigned int u = __float_as_uint(f);
  return (unsigned short)((u + 0x7FFFu + ((u >> 16) & 1u)) >> 16);
}
static __device__ __forceinline__ float bf2f(unsigned short u) {
  return __uint_as_float(((unsigned int)u) << 16);
}
static __device__ __forceinline__ float sigmoidf_(float x) {
  return 1.f / (1.f + __expf(-x));
}
static __device__ __forceinline__ float tanhf_(float x) {
  return 1.f - 2.f / (__expf(2.f * x) + 1.f);
}

// ---------------- BatchNorm stats (two-stage) ----------------
__global__ __launch_bounds__(256) void bn_partial(const float* __restrict__ x,
                                                  float* __restrict__ psum,
                                                  float* __restrict__ psq) {
  int c = blockIdx.x * 256 + threadIdx.x;
  int r0 = blockIdx.y * 256;
  float s = 0.f, q = 0.f;
#pragma unroll 8
  for (int r = r0; r < r0 + 256; ++r) {
    float v = x[(size_t)r * DIN + c];
    s += v; q += v * v;
  }
  psum[blockIdx.y * DIN + c] = s;
  psq[blockIdx.y * DIN + c] = q;
}

__global__ __launch_bounds__(256) void bn_finalize(const float* __restrict__ psum,
                                                   const float* __restrict__ psq,
                                                   const float* __restrict__ gamma,
                                                   const float* __restrict__ beta,
                                                   float* __restrict__ scale,
                                                   float* __restrict__ shift) {
  int c = blockIdx.x * 256 + threadIdx.x;
  float s = 0.f, q = 0.f;
#pragma unroll
  for (int i = 0; i < 8; ++i) { s += psum[i * DIN + c]; q += psq[i * DIN + c]; }
  float mean = s * (1.f / BATCH);
  float var = q * (1.f / BATCH) - mean * mean;
  float sc = gamma[c] * rsqrtf(var + 1e-5f);
  scale[c] = sc;
  shift[c] = beta[c] - mean * sc;
}

// ---------------- prep ----------------
__global__ __launch_bounds__(256) void cvt_bf16(const float* __restrict__ in,
                                                unsigned short* __restrict__ out, long n) {
  long i = ((long)blockIdx.x * 256 + threadIdx.x) * 8;
  if (i >= n) return;
  float4 a = *(const float4*)(in + i);
  float4 b = *(const float4*)(in + i + 4);
  ushort4 lo, hi;
  lo.x = f2bf(a.x); lo.y = f2bf(a.y); lo.z = f2bf(a.z); lo.w = f2bf(a.w);
  hi.x = f2bf(b.x); hi.y = f2bf(b.y); hi.z = f2bf(b.z); hi.w = f2bf(b.w);
  *(ushort4*)(out + i) = lo;
  *(ushort4*)(out + i + 4) = hi;
}

// Gate-interleaved fused weight: row g' = u*4 + gate (orig g = gate*512 + u)
__global__ __launch_bounds__(256) void build_wg2(const float* __restrict__ W_hh,
                                                 const float* __restrict__ W_ih,
                                                 const float* __restrict__ b_ih,
                                                 const float* __restrict__ b_hh,
                                                 unsigned short* __restrict__ Wg2,
                                                 float* __restrict__ bias2) {
  int gp = blockIdx.x;
  int u = gp >> 2, gate = gp & 3;
  int g = gate * HID + u;
  for (int k = threadIdx.x; k < KG; k += 256) {
    float v = (k < HID) ? W_hh[(size_t)g * HID + k] : W_ih[(size_t)g * 32 + (k - HID)];
    Wg2[(size_t)gp * KG + k] = f2bf(v);
  }
  if (threadIdx.x == 0) bias2[gp] = b_ih[g] + b_hh[g];
}

// ---------------- GEMM1 (proven): xs = norm(x) @ W^T + b_in -> [T][B][32] bf16 ----------------
template<int BF16B>
__global__ __launch_bounds__(256) void gemm1_old(const float* __restrict__ x,
                                                 const float* __restrict__ scale,
                                                 const float* __restrict__ shift,
                                                 const void* __restrict__ Bsrc,
                                                 const float* __restrict__ b_in,
                                                 unsigned short* __restrict__ xs) {
  __shared__ unsigned short As[128 * 40];
  __shared__ unsigned short Bs[128 * 40];
  const int tid = threadIdx.x;
  const int lane = tid & 63;
  const int wave = tid >> 6;
  const int wm = (wave >> 1) * 64, wn = (wave & 1) * 64;
  const int bn = blockIdx.x * 128, bm = blockIdx.y * 128;
  const int lr = lane & 15;
  const int kq = (lane >> 4) * 8;

  f32x4 acc[4][4] = {};

  for (int k0 = 0; k0 < DIN; k0 += 32) {
#pragma unroll
    for (int i = 0; i < 4; ++i) {
      int idx = tid + i * 256;
      int row = idx >> 3, c4 = (idx & 7) * 4;
      float4 v = *(const float4*)&x[(size_t)(bm + row) * DIN + k0 + c4];
      float4 sc = *(const float4*)&scale[k0 + c4];
      float4 sh = *(const float4*)&shift[k0 + c4];
      ushort4 o;
      o.x = f2bf(v.x * sc.x + sh.x);
      o.y = f2bf(v.y * sc.y + sh.y);
      o.z = f2bf(v.z * sc.z + sh.z);
      o.w = f2bf(v.w * sc.w + sh.w);
      *(ushort4*)&As[row * 40 + c4] = o;
    }
    if constexpr (BF16B) {
      const unsigned short* W = (const unsigned short*)Bsrc;
#pragma unroll
      for (int i = 0; i < 2; ++i) {
        int idx = tid + i * 256;
        int row = idx >> 2, cc = (idx & 3) * 8;
        *(int4*)&Bs[row * 40 + cc] = *(const int4*)&W[(size_t)(bn + row) * DIN + k0 + cc];
      }
    } else {
      const float* W = (const float*)Bsrc;
#pragma unroll
      for (int i = 0; i < 4; ++i) {
        int idx = tid + i * 256;
        int row = idx >> 3, c4 = (idx & 7) * 4;
        float4 v = *(const float4*)&W[(size_t)(bn + row) * DIN + k0 + c4];
        ushort4 o;
        o.x = f2bf(v.x); o.y = f2bf(v.y); o.z = f2bf(v.z); o.w = f2bf(v.w);
        *(ushort4*)&Bs[row * 40 + c4] = o;
      }
    }
    __syncthreads();
    short8 af[4], bfr[4];
#pragma unroll
    for (int i = 0; i < 4; ++i) af[i] = *(const short8*)&As[(wm + i * 16 + lr) * 40 + kq];
#pragma unroll
    for (int j = 0; j < 4; ++j) bfr[j] = *(const short8*)&Bs[(wn + j * 16 + lr) * 40 + kq];
#pragma unroll
    for (int i = 0; i < 4; ++i)
#pragma unroll
      for (int j = 0; j < 4; ++j)
        acc[i][j] = __builtin_amdgcn_mfma_f32_16x16x32_bf16(af[i], bfr[j], acc[i][j], 0, 0, 0);
    __syncthreads();
  }
#pragma unroll
  for (int i = 0; i < 4; ++i)
#pragma unroll
    for (int j = 0; j < 4; ++j)
#pragma unroll
      for (int r = 0; r < 4; ++r) {
        int row = bm + wm + i * 16 + (lane >> 4) * 4 + r;
        int col = bn + wn + j * 16 + lr;
        float val = acc[i][j][r] + b_in[col];
        xs[((size_t)(col >> 5) * BATCH + row) * 32 + (col & 31)] = f2bf(val);
      }
}

// ---------------- software grid barrier (normal launch, device-scope atomics) ----------------
static __device__ __forceinline__ void grid_barrier(int* bar, int t) {
  __threadfence();             // release: make this block's h stores device-visible
  __syncthreads();             // all threads of block have fenced
  if (threadIdx.x == 0) {
    if (atomicAdd(&bar[0], 1) == NBLK - 1) {
      atomicExch(&bar[0], 0);
      __threadfence();
      atomicExch(&bar[1], t + 1);      // publish generation t+1
    } else {
      while (atomicAdd(&bar[1], 0) < t + 1) {
        __builtin_amdgcn_s_sleep(2);
      }
    }
  }
  __syncthreads();
  __threadfence();             // acquire: invalidate stale cached h lines
}

// ---------------- persistent LSTM: all 256 steps, one normal kernel ----------------
// LDS union: staging As[128][72]+Bs[128][72] (36864 B) <-> gt[64][132] f32 (33792 B)
__global__ __launch_bounds__(256, 1) void lstm_persist(const unsigned short* __restrict__ xs,
                                                       const unsigned short* __restrict__ Wg2,
                                                       const float* __restrict__ bias2,
                                                       unsigned short* __restrict__ h0,
                                                       unsigned short* __restrict__ h1,
                                                       int* __restrict__ bar) {
  __shared__ __align__(16) char smem[36864];
  unsigned short* As = (unsigned short*)smem;            // [128][72]
  unsigned short* Bs = (unsigned short*)(smem + 18432);  // [128][72]
  float* gt = (float*)smem;                              // [64][132] (union)

  const int tid = threadIdx.x, lane = tid & 63, wave = tid >> 6;
  const int bid = blockIdx.x;
  const int i4 = bid >> 3;
  const int bn = ((bid & 7) * 2 + (i4 & 1)) * 128;   // XCD-stripe: XCD owns 2 N-tiles
  const int bm = (i4 >> 1) * 128;
  const int wm = (wave >> 1) * 64, wn = (wave & 1) * 64;
  const int lr = lane & 15, kq = (lane >> 4) * 8;
  const int r0 = tid >> 3;          // 0..31
  const int ch = (tid & 7) * 8;     // 0..56

  float biasr[4];
#pragma unroll
  for (int b2 = 0; b2 < 4; ++b2) biasr[b2] = bias2[bn + wn + b2 * 16 + lr];

  float creg[2][2][4] = {};   // cell state in registers (block owns its slice exclusively)

  for (int t = 0; t < SEQ; ++t) {
    const unsigned short* hin = (t & 1) ? h1 : h0;
    unsigned short* hout      = (t & 1) ? h0 : h1;
    const unsigned short* xrow = xs + ((size_t)t * BATCH + bm) * 32;

    int4 pa[4], pb[4], ta0, ta1, tb0, tb1;
#pragma unroll
    for (int p = 0; p < 4; ++p) {
      pa[p] = *(const int4*)&hin[(size_t)(bm + r0 + p * 32) * HID + ch];
      pb[p] = *(const int4*)&Wg2[(size_t)(bn + r0 + p * 32) * KG + ch];
    }
    f32x4 acc[4][4] = {};

    // 8 full BK=64 phases over h, then one BK=32 tail phase over x
    for (int kt = 0; kt < 8; ++kt) {
      __syncthreads();   // prior ds_reads (or prev-step gt reads) done
#pragma unroll
      for (int p = 0; p < 4; ++p) {
        *(int4*)&As[(r0 + p * 32) * 72 + ch] = pa[p];
        *(int4*)&Bs[(r0 + p * 32) * 72 + ch] = pb[p];
      }
      __syncthreads();   // LDS ready
      if (kt < 7) {
        const int k1 = (kt + 1) * 64;
#pragma unroll
        for (int p = 0; p < 4; ++p) {
          pa[p] = *(const int4*)&hin[(size_t)(bm + r0 + p * 32) * HID + k1 + ch];
          pb[p] = *(const int4*)&Wg2[(size_t)(bn + r0 + p * 32) * KG + k1 + ch];
        }
      } else {           // prefetch the 32-wide x tail
        ta0 = *(const int4*)&xrow[(size_t)(tid >> 2) * 32 + (tid & 3) * 8];
        ta1 = *(const int4*)&xrow[(size_t)((tid >> 2) + 64) * 32 + (tid & 3) * 8];
        tb0 = *(const int4*)&Wg2[(size_t)(bn + (tid >> 2)) * KG + HID + (tid & 3) * 8];
        tb1 = *(const int4*)&Wg2[(size_t)(bn + (tid >> 2) + 64) * KG + HID + (tid & 3) * 8];
      }
#pragma unroll
      for (int kh = 0; kh < 2; ++kh) {
        short8 af[4], bv[4];
#pragma unroll
        for (int a2 = 0; a2 < 4; ++a2)
          af[a2] = *(const short8*)&As[(wm + a2 * 16 + lr) * 72 + kh * 32 + kq];
#pragma unroll
        for (int b2 = 0; b2 < 4; ++b2)
          bv[b2] = *(const short8*)&Bs[(wn + b2 * 16 + lr) * 72 + kh * 32 + kq];
#pragma unroll
        for (int a2 = 0; a2 < 4; ++a2)
#pragma unroll
          for (int b2 = 0; b2 < 4; ++b2)
            acc[a2][b2] = __builtin_amdgcn_mfma_f32_16x16x32_bf16(af[a2], bv[b2], acc[a2][b2], 0, 0, 0);
      }
    }
    // tail phase: K = 512..543 (x part)
    __syncthreads();
    *(int4*)&As[(tid >> 2) * 72 + (tid & 3) * 8] = ta0;
    *(int4*)&As[((tid >> 2) + 64) * 72 + (tid & 3) * 8] = ta1;
    *(int4*)&Bs[(tid >> 2) * 72 + (tid & 3) * 8] = tb0;
    *(int4*)&Bs[((tid >> 2) + 64) * 72 + (tid & 3) * 8] = tb1;
    __syncthreads();
    {
      short8 af[4], bv[4];
#pragma unroll
      for (int a2 = 0; a2 < 4; ++a2)
        af[a2] = *(const short8*)&As[(wm + a2 * 16 + lr) * 72 + kq];
#pragma unroll
      for (int b2 = 0; b2 < 4; ++b2)
        bv[b2] = *(const short8*)&Bs[(wn + b2 * 16 + lr) * 72 + kq];
#pragma unroll
      for (int a2 = 0; a2 < 4; ++a2)
#pragma unroll
        for (int b2 = 0; b2 < 4; ++b2)
          acc[a2][b2] = __builtin_amdgcn_mfma_f32_16x16x32_bf16(af[a2], bv[b2], acc[a2][b2], 0, 0, 0);
    }

    // ---- two half-tile passes: gates -> gt (union over staging) -> fused cell ----
#pragma unroll
    for (int half = 0; half < 2; ++half) {
      __syncthreads();   // half 0: last MFMA ds_reads done; half 1: prev gt reads done
      if ((wm >> 6) == half) {
#pragma unroll
        for (int a2 = 0; a2 < 4; ++a2)
#pragma unroll
          for (int b2 = 0; b2 < 4; ++b2) {
            const int colb = wn + b2 * 16 + lr;
            const int lrow0 = a2 * 16 + (lane >> 4) * 4;
#pragma unroll
            for (int r = 0; r < 4; ++r)
              gt[(lrow0 + r) * 132 + colb] = acc[a2][b2][r] + biasr[b2];
          }
      }
      __syncthreads();   // gt ready
#pragma unroll
      for (int p = 0; p < 2; ++p) {
        const int lrow = p * 32 + (tid >> 3), q = tid & 7;
        const float* g = &gt[lrow * 132 + q * 16];
        float* cr = creg[half][p];
        ushort4 hv;
#pragma unroll
        for (int k = 0; k < 4; ++k) {
          float4 gk = *(const float4*)(g + k * 4);
          float iv = sigmoidf_(gk.x);
          float fv = sigmoidf_(gk.y);
          float gv = tanhf_(gk.z);
          float ov = sigmoidf_(gk.w);
          float ccn = fv * cr[k] + iv * gv;
          cr[k] = ccn;
          ((unsigned short*)&hv)[k] = f2bf(ov * tanhf_(ccn));
        }
        *(ushort4*)&hout[(size_t)(bm + half * 64 + lrow) * HID + (bn >> 2) + q * 4] = hv;
      }
    }

    grid_barrier(bar, t);
  }
}

// ---------------- final GEMV ----------------
__global__ __launch_bounds__(64) void gemv_out(const unsigned short* __restrict__ h,
                                               const float* __restrict__ Wout,
                                               float* __restrict__ out) {
  int b = blockIdx.x;
  int lane = threadIdx.x;
  float s = 0.f;
#pragma unroll
  for (int i = 0; i < 8; ++i) {
    int u = lane + i * 64;
    s += bf2f(h[(size_t)b * HID + u]) * Wout[u];
  }
#pragma unroll
  for (int off = 32; off > 0; off >>= 1) s += __shfl_down(s, off);
  if (lane == 0) out[b] = s;
}

// ---------------- host ----------------
extern "C" void kernel_launch(void* const* d_in, const int* in_sizes, int n_in,
                              void* d_out, int out_size, void* d_ws, size_t ws_size,
                              hipStream_t stream) {
  const float* x     = (const float*)d_in[0];
  const float* gamma = (const float*)d_in[1];
  const float* beta  = (const float*)d_in[2];
  const float* W_in  = (const float*)d_in[3];
  const float* b_in  = (const float*)d_in[4];
  const float* W_ih  = (const float*)d_in[5];
  const float* W_hh  = (const float*)d_in[6];
  const float* b_ih  = (const float*)d_in[7];
  const float* b_hh  = (const float*)d_in[8];
  const float* W_out = (const float*)d_in[9];
  float* out = (float*)d_out;

  // workspace layout (bytes) — identical to the R5-proven layout:
  //   0         scale[8192] f32                32768
  //   32768     shift[8192] f32                32768
  //   65536     bias2[2048] f32                 8192
  //   73728     Wg2 bf16 [2048][544]         2228224
  //   2301952   h0  bf16 [2048][512]         2097152
  //   4399104   h1  bf16 [2048][512]         2097152
  //   6496256   barrier int[16] (old cbuf slot)
  //   10690560  xs  bf16 [256][2048][32]    33554432
  //   44244992  BN partials                   524288
  //   44769280  WinB bf16 [8192][8192]     134217728 (optional)
  char* ws = (char*)d_ws;
  float* scale = (float*)(ws + 0);
  float* shift = (float*)(ws + 32768);
  float* bias2 = (float*)(ws + 65536);
  unsigned short* Wg2 = (unsigned short*)(ws + 73728);
  unsigned short* h0  = (unsigned short*)(ws + 2301952);
  unsigned short* h1  = (unsigned short*)(ws + 4399104);
  int* bar = (int*)(ws + 6496256);
  unsigned short* xs  = (unsigned short*)(ws + 10690560);
  float* psum = (float*)(ws + 44244992);
  float* psq  = psum + 8 * DIN;
  unsigned short* WinB = (unsigned short*)(ws + 44769280);
  const bool useWinB = ws_size >= (44769280ull + 134217728ull);

  hipMemsetAsync(h0, 0, (size_t)BATCH * HID * 2, stream);
  hipMemsetAsync(bar, 0, 64, stream);

  bn_partial<<<dim3(32, 8), 256, 0, stream>>>(x, psum, psq);
  bn_finalize<<<32, 256, 0, stream>>>(psum, psq, gamma, beta, scale, shift);
  build_wg2<<<G4, 256, 0, stream>>>(W_hh, W_ih, b_ih, b_hh, Wg2, bias2);

  if (useWinB) {
    cvt_bf16<<<32768, 256, 0, stream>>>(W_in, WinB, (long)DIN * DIN);
    gemm1_old<1><<<dim3(64, 16), 256, 0, stream>>>(x, scale, shift, WinB, b_in, xs);
  } else {
    gemm1_old<0><<<dim3(64, 16), 256, 0, stream>>>(x, scale, shift, W_in, b_in, xs);
  }

  lstm_persist<<<NBLK, 256, 0, stream>>>(xs, Wg2, bias2, h0, h1, bar);

  gemv_out<<<BATCH, 64, 0, stream>>>(h0, W_out, out);
}

// Round 8
// 18453.410 us; speedup vs baseline: 1.0574x; 1.0574x over previous
//
#include <hip/hip_runtime.h>

#define SEQ   256
#define DIN   8192
#define BATCH 2048
#define HID   512
#define G4    2048   // 4*HID
#define KG    544    // HID + 32
#define NBLK  256
#define FLAG_STRIDE 16   // ints; 64 B between flags

typedef __attribute__((ext_vector_type(8))) short short8;
typedef __attribute__((ext_vector_type(4))) float f32x4;

static __device__ __forceinline__ unsigned short f2bf(float f) {
  unsigned int u = __float_as_uint(f);
  return (unsigned short)((u + 0x7FFFu + ((u >> 16) & 1u)) >> 16);
}
static __device__ __forceinline__ float bf2f(unsigned short u) {
  return __uint_as_float(((unsigned int)u) << 16);
}
static __device__ __forceinline__ float sigmoidf_(float x) {
  return 1.f / (1.f + __expf(-x));
}
static __device__ __forceinline__ float tanhf_(float x) {
  return 1.f - 2.f / (__expf(2.f * x) + 1.f);
}

// ---------------- BatchNorm stats (two-stage) ----------------
__global__ __launch_bounds__(256) void bn_partial(const float* __restrict__ x,
                                                  float* __restrict__ psum,
                                                  float* __restrict__ psq) {
  int c = blockIdx.x * 256 + threadIdx.x;
  int r0 = blockIdx.y * 256;
  float s = 0.f, q = 0.f;
#pragma unroll 8
  for (int r = r0; r < r0 + 256; ++r) {
    float v = x[(size_t)r * DIN + c];
    s += v; q += v * v;
  }
  psum[blockIdx.y * DIN + c] = s;
  psq[blockIdx.y * DIN + c] = q;
}

__global__ __launch_bounds__(256) void bn_finalize(const float* __restrict__ psum,
                                                   const float* __restrict__ psq,
                                                   const float* __restrict__ gamma,
                                                   const float* __restrict__ beta,
                                                   float* __restrict__ scale,
                                                   float* __restrict__ shift) {
  int c = blockIdx.x * 256 + threadIdx.x;
  float s = 0.f, q = 0.f;
#pragma unroll
  for (int i = 0; i < 8; ++i) { s += psum[i * DIN + c]; q += psq[i * DIN + c]; }
  float mean = s * (1.f / BATCH);
  float var = q * (1.f / BATCH) - mean * mean;
  float sc = gamma[c] * rsqrtf(var + 1e-5f);
  scale[c] = sc;
  shift[c] = beta[c] - mean * sc;
}

// ---------------- prep ----------------
__global__ __launch_bounds__(256) void cvt_bf16(const float* __restrict__ in,
                                                unsigned short* __restrict__ out, long n) {
  long i = ((long)blockIdx.x * 256 + threadIdx.x) * 8;
  if (i >= n) return;
  float4 a = *(const float4*)(in + i);
  float4 b = *(const float4*)(in + i + 4);
  ushort4 lo, hi;
  lo.x = f2bf(a.x); lo.y = f2bf(a.y); lo.z = f2bf(a.z); lo.w = f2bf(a.w);
  hi.x = f2bf(b.x); hi.y = f2bf(b.y); hi.z = f2bf(b.z); hi.w = f2bf(b.w);
  *(ushort4*)(out + i) = lo;
  *(ushort4*)(out + i + 4) = hi;
}

// Gate-interleaved fused weight: row g' = u*4 + gate (orig g = gate*512 + u)
__global__ __launch_bounds__(256) void build_wg2(const float* __restrict__ W_hh,
                                                 const float* __restrict__ W_ih,
                                                 const float* __restrict__ b_ih,
                                                 const float* __restrict__ b_hh,
                                                 unsigned short* __restrict__ Wg2,
                                                 float* __restrict__ bias2) {
  int gp = blockIdx.x;
  int u = gp >> 2, gate = gp & 3;
  int g = gate * HID + u;
  for (int k = threadIdx.x; k < KG; k += 256) {
    float v = (k < HID) ? W_hh[(size_t)g * HID + k] : W_ih[(size_t)g * 32 + (k - HID)];
    Wg2[(size_t)gp * KG + k] = f2bf(v);
  }
  if (threadIdx.x == 0) bias2[gp] = b_ih[g] + b_hh[g];
}

// ---------------- GEMM1 (proven): xs = norm(x) @ W^T + b_in -> [T][B][32] bf16 ----------------
template<int BF16B>
__global__ __launch_bounds__(256) void gemm1_old(const float* __restrict__ x,
                                                 const float* __restrict__ scale,
                                                 const float* __restrict__ shift,
                                                 const void* __restrict__ Bsrc,
                                                 const float* __restrict__ b_in,
                                                 unsigned short* __restrict__ xs) {
  __shared__ unsigned short As[128 * 40];
  __shared__ unsigned short Bs[128 * 40];
  const int tid = threadIdx.x;
  const int lane = tid & 63;
  const int wave = tid >> 6;
  const int wm = (wave >> 1) * 64, wn = (wave & 1) * 64;
  const int bn = blockIdx.x * 128, bm = blockIdx.y * 128;
  const int lr = lane & 15;
  const int kq = (lane >> 4) * 8;

  f32x4 acc[4][4] = {};

  for (int k0 = 0; k0 < DIN; k0 += 32) {
#pragma unroll
    for (int i = 0; i < 4; ++i) {
      int idx = tid + i * 256;
      int row = idx >> 3, c4 = (idx & 7) * 4;
      float4 v = *(const float4*)&x[(size_t)(bm + row) * DIN + k0 + c4];
      float4 sc = *(const float4*)&scale[k0 + c4];
      float4 sh = *(const float4*)&shift[k0 + c4];
      ushort4 o;
      o.x = f2bf(v.x * sc.x + sh.x);
      o.y = f2bf(v.y * sc.y + sh.y);
      o.z = f2bf(v.z * sc.z + sh.z);
      o.w = f2bf(v.w * sc.w + sh.w);
      *(ushort4*)&As[row * 40 + c4] = o;
    }
    if constexpr (BF16B) {
      const unsigned short* W = (const unsigned short*)Bsrc;
#pragma unroll
      for (int i = 0; i < 2; ++i) {
        int idx = tid + i * 256;
        int row = idx >> 2, cc = (idx & 3) * 8;
        *(int4*)&Bs[row * 40 + cc] = *(const int4*)&W[(size_t)(bn + row) * DIN + k0 + cc];
      }
    } else {
      const float* W = (const float*)Bsrc;
#pragma unroll
      for (int i = 0; i < 4; ++i) {
        int idx = tid + i * 256;
        int row = idx >> 3, c4 = (idx & 7) * 4;
        float4 v = *(const float4*)&W[(size_t)(bn + row) * DIN + k0 + c4];
        ushort4 o;
        o.x = f2bf(v.x); o.y = f2bf(v.y); o.z = f2bf(v.z); o.w = f2bf(v.w);
        *(ushort4*)&Bs[row * 40 + c4] = o;
      }
    }
    __syncthreads();
    short8 af[4], bfr[4];
#pragma unroll
    for (int i = 0; i < 4; ++i) af[i] = *(const short8*)&As[(wm + i * 16 + lr) * 40 + kq];
#pragma unroll
    for (int j = 0; j < 4; ++j) bfr[j] = *(const short8*)&Bs[(wn + j * 16 + lr) * 40 + kq];
#pragma unroll
    for (int i = 0; i < 4; ++i)
#pragma unroll
      for (int j = 0; j < 4; ++j)
        acc[i][j] = __builtin_amdgcn_mfma_f32_16x16x32_bf16(af[i], bfr[j], acc[i][j], 0, 0, 0);
    __syncthreads();
  }
#pragma unroll
  for (int i = 0; i < 4; ++i)
#pragma unroll
    for (int j = 0; j < 4; ++j)
#pragma unroll
      for (int r = 0; r < 4; ++r) {
        int row = bm + wm + i * 16 + (lane >> 4) * 4 + r;
        int col = bn + wn + j * 16 + lr;
        float val = acc[i][j][r] + b_in[col];
        xs[((size_t)(col >> 5) * BATCH + row) * 32 + (col & 31)] = f2bf(val);
      }
}

// ---------------- persistent LSTM with distributed-flag grid barrier ----------------
// LDS union: staging As[128][72]+Bs[128][72] (36864 B) <-> gt[64][132] f32 (33792 B)
__global__ __launch_bounds__(256, 1) void lstm_persist(const unsigned short* __restrict__ xs,
                                                       const unsigned short* __restrict__ Wg2,
                                                       const float* __restrict__ bias2,
                                                       unsigned short* __restrict__ h0,
                                                       unsigned short* __restrict__ h1,
                                                       int* __restrict__ bar,
                                                       int* __restrict__ flags) {
  __shared__ __align__(16) char smem[36864];
  __shared__ int smflag;
  unsigned short* As = (unsigned short*)smem;            // [128][72]
  unsigned short* Bs = (unsigned short*)(smem + 18432);  // [128][72]
  float* gt = (float*)smem;                              // [64][132] (union)

  const int tid = threadIdx.x, lane = tid & 63, wave = tid >> 6;
  const int bid = blockIdx.x;
  const int i4 = bid >> 3;
  const int bn = ((bid & 7) * 2 + (i4 & 1)) * 128;   // XCD-stripe: XCD owns 2 N-tiles
  const int bm = (i4 >> 1) * 128;
  const int wm = (wave >> 1) * 64, wn = (wave & 1) * 64;
  const int lr = lane & 15, kq = (lane >> 4) * 8;
  const int r0 = tid >> 3;          // 0..31
  const int ch = (tid & 7) * 8;     // 0..56

  float biasr[4];
#pragma unroll
  for (int b2 = 0; b2 < 4; ++b2) biasr[b2] = bias2[bn + wn + b2 * 16 + lr];

  // t-invariant Wg2 prefetches, hoisted out of the step loop
  int4 pbF[4], tb0, tb1;
#pragma unroll
  for (int p = 0; p < 4; ++p)
    pbF[p] = *(const int4*)&Wg2[(size_t)(bn + r0 + p * 32) * KG + ch];
  tb0 = *(const int4*)&Wg2[(size_t)(bn + (tid >> 2)) * KG + HID + (tid & 3) * 8];
  tb1 = *(const int4*)&Wg2[(size_t)(bn + (tid >> 2) + 64) * KG + HID + (tid & 3) * 8];

  float creg[2][2][4] = {};   // cell state in registers (block owns its slice exclusively)

  for (int t = 0; t < SEQ; ++t) {
    const unsigned short* hin = (t & 1) ? h1 : h0;
    unsigned short* hout      = (t & 1) ? h0 : h1;
    const unsigned short* xrow = xs + ((size_t)t * BATCH + bm) * 32;

    int4 pa[4], pb[4], ta0, ta1;
#pragma unroll
    for (int p = 0; p < 4; ++p) {
      pa[p] = *(const int4*)&hin[(size_t)(bm + r0 + p * 32) * HID + ch];
      pb[p] = pbF[p];
    }
    f32x4 acc[4][4] = {};

    // 8 full BK=64 phases over h, then one BK=32 tail phase over x
    for (int kt = 0; kt < 8; ++kt) {
      __syncthreads();   // prior ds_reads (or prev-step gt reads) done
#pragma unroll
      for (int p = 0; p < 4; ++p) {
        *(int4*)&As[(r0 + p * 32) * 72 + ch] = pa[p];
        *(int4*)&Bs[(r0 + p * 32) * 72 + ch] = pb[p];
      }
      __syncthreads();   // LDS ready
      if (kt < 7) {
        const int k1 = (kt + 1) * 64;
#pragma unroll
        for (int p = 0; p < 4; ++p) {
          pa[p] = *(const int4*)&hin[(size_t)(bm + r0 + p * 32) * HID + k1 + ch];
          pb[p] = *(const int4*)&Wg2[(size_t)(bn + r0 + p * 32) * KG + k1 + ch];
        }
      } else {           // prefetch the 32-wide x tail
        ta0 = *(const int4*)&xrow[(size_t)(tid >> 2) * 32 + (tid & 3) * 8];
        ta1 = *(const int4*)&xrow[(size_t)((tid >> 2) + 64) * 32 + (tid & 3) * 8];
      }
#pragma unroll
      for (int kh = 0; kh < 2; ++kh) {
        short8 af[4], bv[4];
#pragma unroll
        for (int a2 = 0; a2 < 4; ++a2)
          af[a2] = *(const short8*)&As[(wm + a2 * 16 + lr) * 72 + kh * 32 + kq];
#pragma unroll
        for (int b2 = 0; b2 < 4; ++b2)
          bv[b2] = *(const short8*)&Bs[(wn + b2 * 16 + lr) * 72 + kh * 32 + kq];
#pragma unroll
        for (int a2 = 0; a2 < 4; ++a2)
#pragma unroll
          for (int b2 = 0; b2 < 4; ++b2)
            acc[a2][b2] = __builtin_amdgcn_mfma_f32_16x16x32_bf16(af[a2], bv[b2], acc[a2][b2], 0, 0, 0);
      }
    }
    // tail phase: K = 512..543 (x part)
    __syncthreads();
    *(int4*)&As[(tid >> 2) * 72 + (tid & 3) * 8] = ta0;
    *(int4*)&As[((tid >> 2) + 64) * 72 + (tid & 3) * 8] = ta1;
    *(int4*)&Bs[(tid >> 2) * 72 + (tid & 3) * 8] = tb0;
    *(int4*)&Bs[((tid >> 2) + 64) * 72 + (tid & 3) * 8] = tb1;
    __syncthreads();
    {
      short8 af[4], bv[4];
#pragma unroll
      for (int a2 = 0; a2 < 4; ++a2)
        af[a2] = *(const short8*)&As[(wm + a2 * 16 + lr) * 72 + kq];
#pragma unroll
      for (int b2 = 0; b2 < 4; ++b2)
        bv[b2] = *(const short8*)&Bs[(wn + b2 * 16 + lr) * 72 + kq];
#pragma unroll
      for (int a2 = 0; a2 < 4; ++a2)
#pragma unroll
        for (int b2 = 0; b2 < 4; ++b2)
          acc[a2][b2] = __builtin_amdgcn_mfma_f32_16x16x32_bf16(af[a2], bv[b2], acc[a2][b2], 0, 0, 0);
    }

    // ---- two half-tile passes: gates -> gt (union over staging) -> fused cell ----
#pragma unroll
    for (int half = 0; half < 2; ++half) {
      __syncthreads();   // half 0: last MFMA ds_reads done; half 1: prev gt reads done
      if ((wm >> 6) == half) {
#pragma unroll
        for (int a2 = 0; a2 < 4; ++a2)
#pragma unroll
          for (int b2 = 0; b2 < 4; ++b2) {
            const int colb = wn + b2 * 16 + lr;
            const int lrow0 = a2 * 16 + (lane >> 4) * 4;
#pragma unroll
            for (int r = 0; r < 4; ++r)
              gt[(lrow0 + r) * 132 + colb] = acc[a2][b2][r] + biasr[b2];
          }
      }
      __syncthreads();   // gt ready
#pragma unroll
      for (int p = 0; p < 2; ++p) {
        const int lrow = p * 32 + (tid >> 3), q = tid & 7;
        const float* g = &gt[lrow * 132 + q * 16];
        float* cr = creg[half][p];
        ushort4 hv;
#pragma unroll
        for (int k = 0; k < 4; ++k) {
          float4 gk = *(const float4*)(g + k * 4);
          float iv = sigmoidf_(gk.x);
          float fv = sigmoidf_(gk.y);
          float gv = tanhf_(gk.z);
          float ov = sigmoidf_(gk.w);
          float ccn = fv * cr[k] + iv * gv;
          cr[k] = ccn;
          ((unsigned short*)&hv)[k] = f2bf(ov * tanhf_(ccn));
        }
        *(ushort4*)&hout[(size_t)(bm + half * 64 + lrow) * HID + (bn >> 2) + q * 4] = hv;
      }
    }

    // ---- distributed-flag grid barrier (same fence semantics as R7) ----
    __threadfence();             // release: make this block's h stores device-visible
    __syncthreads();
    if (tid == 0)
      smflag = (atomicAdd(&bar[0], 1) == NBLK - 1) ? 1 : 0;
    __syncthreads();
    if (smflag) {                // this block releases everyone
      if (tid == 0) atomicExch(&bar[0], 0);
      __syncthreads();           // reset complete before any flag is published
      atomicExch(&flags[tid * FLAG_STRIDE], t + 1);   // 256 flags, distinct lines
    } else if (tid == 0) {
      while (atomicAdd(&flags[bid * FLAG_STRIDE], 0) < t + 1)
        __builtin_amdgcn_s_sleep(1);
    }
    __syncthreads();
    __threadfence();             // acquire: drop stale cached h lines
  }
}

// ---------------- final GEMV ----------------
__global__ __launch_bounds__(64) void gemv_out(const unsigned short* __restrict__ h,
                                               const float* __restrict__ Wout,
                                               float* __restrict__ out) {
  int b = blockIdx.x;
  int lane = threadIdx.x;
  float s = 0.f;
#pragma unroll
  for (int i = 0; i < 8; ++i) {
    int u = lane + i * 64;
    s += bf2f(h[(size_t)b * HID + u]) * Wout[u];
  }
#pragma unroll
  for (int off = 32; off > 0; off >>= 1) s += __shfl_down(s, off);
  if (lane == 0) out[b] = s;
}

// ---------------- host ----------------
extern "C" void kernel_launch(void* const* d_in, const int* in_sizes, int n_in,
                              void* d_out, int out_size, void* d_ws, size_t ws_size,
                              hipStream_t stream) {
  const float* x     = (const float*)d_in[0];
  const float* gamma = (const float*)d_in[1];
  const float* beta  = (const float*)d_in[2];
  const float* W_in  = (const float*)d_in[3];
  const float* b_in  = (const float*)d_in[4];
  const float* W_ih  = (const float*)d_in[5];
  const float* W_hh  = (const float*)d_in[6];
  const float* b_ih  = (const float*)d_in[7];
  const float* b_hh  = (const float*)d_in[8];
  const float* W_out = (const float*)d_in[9];
  float* out = (float*)d_out;

  // workspace layout (bytes) — R5-proven layout; barrier+flags in the old cbuf slot:
  //   0         scale[8192] f32                32768
  //   32768     shift[8192] f32                32768
  //   65536     bias2[2048] f32                 8192
  //   73728     Wg2 bf16 [2048][544]         2228224
  //   2301952   h0  bf16 [2048][512]         2097152
  //   4399104   h1  bf16 [2048][512]         2097152
  //   6496256   bar int[16] + flags int[256*16] (64 + 16384)
  //   10690560  xs  bf16 [256][2048][32]    33554432
  //   44244992  BN partials                   524288
  //   44769280  WinB bf16 [8192][8192]     134217728 (optional)
  char* ws = (char*)d_ws;
  float* scale = (float*)(ws + 0);
  float* shift = (float*)(ws + 32768);
  float* bias2 = (float*)(ws + 65536);
  unsigned short* Wg2 = (unsigned short*)(ws + 73728);
  unsigned short* h0  = (unsigned short*)(ws + 2301952);
  unsigned short* h1  = (unsigned short*)(ws + 4399104);
  int* bar   = (int*)(ws + 6496256);
  int* flags = (int*)(ws + 6496256 + 64);
  unsigned short* xs  = (unsigned short*)(ws + 10690560);
  float* psum = (float*)(ws + 44244992);
  float* psq  = psum + 8 * DIN;
  unsigned short* WinB = (unsigned short*)(ws + 44769280);
  const bool useWinB = ws_size >= (44769280ull + 134217728ull);

  hipMemsetAsync(h0, 0, (size_t)BATCH * HID * 2, stream);
  hipMemsetAsync(bar, 0, 64 + NBLK * FLAG_STRIDE * 4, stream);   // captured: resets every replay

  bn_partial<<<dim3(32, 8), 256, 0, stream>>>(x, psum, psq);
  bn_finalize<<<32, 256, 0, stream>>>(psum, psq, gamma, beta, scale, shift);
  build_wg2<<<G4, 256, 0, stream>>>(W_hh, W_ih, b_ih, b_hh, Wg2, bias2);

  if (useWinB) {
    cvt_bf16<<<32768, 256, 0, stream>>>(W_in, WinB, (long)DIN * DIN);
    gemm1_old<1><<<dim3(64, 16), 256, 0, stream>>>(x, scale, shift, WinB, b_in, xs);
  } else {
    gemm1_old<0><<<dim3(64, 16), 256, 0, stream>>>(x, scale, shift, W_in, b_in, xs);
  }

  lstm_persist<<<NBLK, 256, 0, stream>>>(xs, Wg2, bias2, h0, h1, bar, flags);

  gemv_out<<<BATCH, 64, 0, stream>>>(h0, W_out, out);
}

// Round 9
// 6876.208 us; speedup vs baseline: 2.8377x; 2.6837x over previous
//
#include <hip/hip_runtime.h>

#define SEQ   256
#define DIN   8192
#define BATCH 2048
#define HID   512
#define G4    2048   // 4*HID
#define KG    544    // HID + 32
#define NBLK  256
#define FLAG_STRIDE 16   // ints; 64 B between flags

typedef __attribute__((ext_vector_type(8))) short short8;
typedef __attribute__((ext_vector_type(4))) float f32x4;

static __device__ __forceinline__ unsigned short f2bf(float f) {
  unsigned int u = __float_as_uint(f);
  return (unsigned short)((u + 0x7FFFu + ((u >> 16) & 1u)) >> 16);
}
static __device__ __forceinline__ float bf2f(unsigned short u) {
  return __uint_as_float(((unsigned int)u) << 16);
}
static __device__ __forceinline__ float sigmoidf_(float x) {
  return 1.f / (1.f + __expf(-x));
}
static __device__ __forceinline__ float tanhf_(float x) {
  return 1.f - 2.f / (__expf(2.f * x) + 1.f);
}

// coherent (agent-scope, L3) 16B h-load as two u64s — no cache maintenance
#define HLOAD(dst, ptr) do {                                                      \
    const unsigned long long* _q = (const unsigned long long*)(ptr);              \
    dst[0] = __hip_atomic_load(_q,     __ATOMIC_RELAXED, __HIP_MEMORY_SCOPE_AGENT); \
    dst[1] = __hip_atomic_load(_q + 1, __ATOMIC_RELAXED, __HIP_MEMORY_SCOPE_AGENT); \
  } while (0)

// ---------------- BatchNorm stats (two-stage) ----------------
__global__ __launch_bounds__(256) void bn_partial(const float* __restrict__ x,
                                                  float* __restrict__ psum,
                                                  float* __restrict__ psq) {
  int c = blockIdx.x * 256 + threadIdx.x;
  int r0 = blockIdx.y * 256;
  float s = 0.f, q = 0.f;
#pragma unroll 8
  for (int r = r0; r < r0 + 256; ++r) {
    float v = x[(size_t)r * DIN + c];
    s += v; q += v * v;
  }
  psum[blockIdx.y * DIN + c] = s;
  psq[blockIdx.y * DIN + c] = q;
}

__global__ __launch_bounds__(256) void bn_finalize(const float* __restrict__ psum,
                                                   const float* __restrict__ psq,
                                                   const float* __restrict__ gamma,
                                                   const float* __restrict__ beta,
                                                   float* __restrict__ scale,
                                                   float* __restrict__ shift) {
  int c = blockIdx.x * 256 + threadIdx.x;
  float s = 0.f, q = 0.f;
#pragma unroll
  for (int i = 0; i < 8; ++i) { s += psum[i * DIN + c]; q += psq[i * DIN + c]; }
  float mean = s * (1.f / BATCH);
  float var = q * (1.f / BATCH) - mean * mean;
  float sc = gamma[c] * rsqrtf(var + 1e-5f);
  scale[c] = sc;
  shift[c] = beta[c] - mean * sc;
}

// ---------------- prep ----------------
__global__ __launch_bounds__(256) void cvt_bf16(const float* __restrict__ in,
                                                unsigned short* __restrict__ out, long n) {
  long i = ((long)blockIdx.x * 256 + threadIdx.x) * 8;
  if (i >= n) return;
  float4 a = *(const float4*)(in + i);
  float4 b = *(const float4*)(in + i + 4);
  ushort4 lo, hi;
  lo.x = f2bf(a.x); lo.y = f2bf(a.y); lo.z = f2bf(a.z); lo.w = f2bf(a.w);
  hi.x = f2bf(b.x); hi.y = f2bf(b.y); hi.z = f2bf(b.z); hi.w = f2bf(b.w);
  *(ushort4*)(out + i) = lo;
  *(ushort4*)(out + i + 4) = hi;
}

// Gate-interleaved fused weight: row g' = u*4 + gate (orig g = gate*512 + u)
__global__ __launch_bounds__(256) void build_wg2(const float* __restrict__ W_hh,
                                                 const float* __restrict__ W_ih,
                                                 const float* __restrict__ b_ih,
                                                 const float* __restrict__ b_hh,
                                                 unsigned short* __restrict__ Wg2,
                                                 float* __restrict__ bias2) {
  int gp = blockIdx.x;
  int u = gp >> 2, gate = gp & 3;
  int g = gate * HID + u;
  for (int k = threadIdx.x; k < KG; k += 256) {
    float v = (k < HID) ? W_hh[(size_t)g * HID + k] : W_ih[(size_t)g * 32 + (k - HID)];
    Wg2[(size_t)gp * KG + k] = f2bf(v);
  }
  if (threadIdx.x == 0) bias2[gp] = b_ih[g] + b_hh[g];
}

// ---------------- GEMM1 (proven): xs = norm(x) @ W^T + b_in -> [T][B][32] bf16 ----------------
template<int BF16B>
__global__ __launch_bounds__(256) void gemm1_old(const float* __restrict__ x,
                                                 const float* __restrict__ scale,
                                                 const float* __restrict__ shift,
                                                 const void* __restrict__ Bsrc,
                                                 const float* __restrict__ b_in,
                                                 unsigned short* __restrict__ xs) {
  __shared__ unsigned short As[128 * 40];
  __shared__ unsigned short Bs[128 * 40];
  const int tid = threadIdx.x;
  const int lane = tid & 63;
  const int wave = tid >> 6;
  const int wm = (wave >> 1) * 64, wn = (wave & 1) * 64;
  const int bn = blockIdx.x * 128, bm = blockIdx.y * 128;
  const int lr = lane & 15;
  const int kq = (lane >> 4) * 8;

  f32x4 acc[4][4] = {};

  for (int k0 = 0; k0 < DIN; k0 += 32) {
#pragma unroll
    for (int i = 0; i < 4; ++i) {
      int idx = tid + i * 256;
      int row = idx >> 3, c4 = (idx & 7) * 4;
      float4 v = *(const float4*)&x[(size_t)(bm + row) * DIN + k0 + c4];
      float4 sc = *(const float4*)&scale[k0 + c4];
      float4 sh = *(const float4*)&shift[k0 + c4];
      ushort4 o;
      o.x = f2bf(v.x * sc.x + sh.x);
      o.y = f2bf(v.y * sc.y + sh.y);
      o.z = f2bf(v.z * sc.z + sh.z);
      o.w = f2bf(v.w * sc.w + sh.w);
      *(ushort4*)&As[row * 40 + c4] = o;
    }
    if constexpr (BF16B) {
      const unsigned short* W = (const unsigned short*)Bsrc;
#pragma unroll
      for (int i = 0; i < 2; ++i) {
        int idx = tid + i * 256;
        int row = idx >> 2, cc = (idx & 3) * 8;
        *(int4*)&Bs[row * 40 + cc] = *(const int4*)&W[(size_t)(bn + row) * DIN + k0 + cc];
      }
    } else {
      const float* W = (const float*)Bsrc;
#pragma unroll
      for (int i = 0; i < 4; ++i) {
        int idx = tid + i * 256;
        int row = idx >> 3, c4 = (idx & 7) * 4;
        float4 v = *(const float4*)&W[(size_t)(bn + row) * DIN + k0 + c4];
        ushort4 o;
        o.x = f2bf(v.x); o.y = f2bf(v.y); o.z = f2bf(v.z); o.w = f2bf(v.w);
        *(ushort4*)&Bs[row * 40 + c4] = o;
      }
    }
    __syncthreads();
    short8 af[4], bfr[4];
#pragma unroll
    for (int i = 0; i < 4; ++i) af[i] = *(const short8*)&As[(wm + i * 16 + lr) * 40 + kq];
#pragma unroll
    for (int j = 0; j < 4; ++j) bfr[j] = *(const short8*)&Bs[(wn + j * 16 + lr) * 40 + kq];
#pragma unroll
    for (int i = 0; i < 4; ++i)
#pragma unroll
      for (int j = 0; j < 4; ++j)
        acc[i][j] = __builtin_amdgcn_mfma_f32_16x16x32_bf16(af[i], bfr[j], acc[i][j], 0, 0, 0);
    __syncthreads();
  }
#pragma unroll
  for (int i = 0; i < 4; ++i)
#pragma unroll
    for (int j = 0; j < 4; ++j)
#pragma unroll
      for (int r = 0; r < 4; ++r) {
        int row = bm + wm + i * 16 + (lane >> 4) * 4 + r;
        int col = bn + wn + j * 16 + lr;
        float val = acc[i][j][r] + b_in[col];
        xs[((size_t)(col >> 5) * BATCH + row) * 32 + (col & 31)] = f2bf(val);
      }
}

// ---------------- persistent LSTM: fence-free, coherent-h, M-group barriers ----------------
// LDS union: staging As[128][72]+Bs[128][72] (36864 B) <-> gt[64][132] f32 (33792 B)
// Block (bm,bn) reads h rows [bm,bm+128) all cols; those are written only by the 16
// blocks sharing bm -> barrier scope = 16-block M-group.
__global__ __launch_bounds__(256, 1) void lstm_persist(const unsigned short* __restrict__ xs,
                                                       const unsigned short* __restrict__ Wg2,
                                                       const float* __restrict__ bias2,
                                                       unsigned short* __restrict__ h0,
                                                       unsigned short* __restrict__ h1,
                                                       int* __restrict__ bar,
                                                       int* __restrict__ flags) {
  __shared__ __align__(16) char smem[36864];
  __shared__ int smflag;
  unsigned short* As = (unsigned short*)smem;            // [128][72]
  unsigned short* Bs = (unsigned short*)(smem + 18432);  // [128][72]
  float* gt = (float*)smem;                              // [64][132] (union)

  const int tid = threadIdx.x, lane = tid & 63, wave = tid >> 6;
  const int bid = blockIdx.x;
  const int i4 = bid >> 3;
  const int bn = ((bid & 7) * 2 + (i4 & 1)) * 128;   // XCD-stripe: XCD owns 2 N-tiles
  const int bm = (i4 >> 1) * 128;
  const int grp = bid >> 4;                          // M-group (same bm): bids [grp*16, grp*16+16)
  const int wm = (wave >> 1) * 64, wn = (wave & 1) * 64;
  const int lr = lane & 15, kq = (lane >> 4) * 8;
  const int r0 = tid >> 3;          // 0..31
  const int ch = (tid & 7) * 8;     // 0..56

  float biasr[4];
#pragma unroll
  for (int b2 = 0; b2 < 4; ++b2) biasr[b2] = bias2[bn + wn + b2 * 16 + lr];

  // t-invariant Wg2 prefetches, hoisted out of the step loop
  int4 pbF[4], tb0, tb1;
#pragma unroll
  for (int p = 0; p < 4; ++p)
    pbF[p] = *(const int4*)&Wg2[(size_t)(bn + r0 + p * 32) * KG + ch];
  tb0 = *(const int4*)&Wg2[(size_t)(bn + (tid >> 2)) * KG + HID + (tid & 3) * 8];
  tb1 = *(const int4*)&Wg2[(size_t)(bn + (tid >> 2) + 64) * KG + HID + (tid & 3) * 8];

  float creg[2][2][4] = {};   // cell state in registers (block owns its slice exclusively)

  for (int t = 0; t < SEQ; ++t) {
    const unsigned short* hin = (t & 1) ? h1 : h0;
    unsigned short* hout      = (t & 1) ? h0 : h1;
    const unsigned short* xrow = xs + ((size_t)t * BATCH + bm) * 32;

    unsigned long long pa[4][2];
    int4 pb[4], ta0, ta1;
#pragma unroll
    for (int p = 0; p < 4; ++p) {
      HLOAD(pa[p], &hin[(size_t)(bm + r0 + p * 32) * HID + ch]);
      pb[p] = pbF[p];
    }
    f32x4 acc[4][4] = {};

    // 8 full BK=64 phases over h, then one BK=32 tail phase over x
    for (int kt = 0; kt < 8; ++kt) {
      __syncthreads();   // prior ds_reads done (also drains vmcnt -> pa ready)
#pragma unroll
      for (int p = 0; p < 4; ++p) {
        *(unsigned long long*)&As[(r0 + p * 32) * 72 + ch] = pa[p][0];
        *(unsigned long long*)&As[(r0 + p * 32) * 72 + ch + 4] = pa[p][1];
        *(int4*)&Bs[(r0 + p * 32) * 72 + ch] = pb[p];
      }
      __syncthreads();   // LDS ready
      if (kt < 7) {
        const int k1 = (kt + 1) * 64;
#pragma unroll
        for (int p = 0; p < 4; ++p) {
          HLOAD(pa[p], &hin[(size_t)(bm + r0 + p * 32) * HID + k1 + ch]);
          pb[p] = *(const int4*)&Wg2[(size_t)(bn + r0 + p * 32) * KG + k1 + ch];
        }
      } else {           // prefetch the 32-wide x tail (xs is read-only: plain cached loads)
        ta0 = *(const int4*)&xrow[(size_t)(tid >> 2) * 32 + (tid & 3) * 8];
        ta1 = *(const int4*)&xrow[(size_t)((tid >> 2) + 64) * 32 + (tid & 3) * 8];
      }
#pragma unroll
      for (int kh = 0; kh < 2; ++kh) {
        short8 af[4], bv[4];
#pragma unroll
        for (int a2 = 0; a2 < 4; ++a2)
          af[a2] = *(const short8*)&As[(wm + a2 * 16 + lr) * 72 + kh * 32 + kq];
#pragma unroll
        for (int b2 = 0; b2 < 4; ++b2)
          bv[b2] = *(const short8*)&Bs[(wn + b2 * 16 + lr) * 72 + kh * 32 + kq];
#pragma unroll
        for (int a2 = 0; a2 < 4; ++a2)
#pragma unroll
          for (int b2 = 0; b2 < 4; ++b2)
            acc[a2][b2] = __builtin_amdgcn_mfma_f32_16x16x32_bf16(af[a2], bv[b2], acc[a2][b2], 0, 0, 0);
      }
    }
    // tail phase: K = 512..543 (x part)
    __syncthreads();
    *(int4*)&As[(tid >> 2) * 72 + (tid & 3) * 8] = ta0;
    *(int4*)&As[((tid >> 2) + 64) * 72 + (tid & 3) * 8] = ta1;
    *(int4*)&Bs[(tid >> 2) * 72 + (tid & 3) * 8] = tb0;
    *(int4*)&Bs[((tid >> 2) + 64) * 72 + (tid & 3) * 8] = tb1;
    __syncthreads();
    {
      short8 af[4], bv[4];
#pragma unroll
      for (int a2 = 0; a2 < 4; ++a2)
        af[a2] = *(const short8*)&As[(wm + a2 * 16 + lr) * 72 + kq];
#pragma unroll
      for (int b2 = 0; b2 < 4; ++b2)
        bv[b2] = *(const short8*)&Bs[(wn + b2 * 16 + lr) * 72 + kq];
#pragma unroll
      for (int a2 = 0; a2 < 4; ++a2)
#pragma unroll
        for (int b2 = 0; b2 < 4; ++b2)
          acc[a2][b2] = __builtin_amdgcn_mfma_f32_16x16x32_bf16(af[a2], bv[b2], acc[a2][b2], 0, 0, 0);
    }

    // ---- two half-tile passes: gates -> gt (union over staging) -> fused cell ----
#pragma unroll
    for (int half = 0; half < 2; ++half) {
      __syncthreads();   // half 0: last MFMA ds_reads done; half 1: prev gt reads done
      if ((wm >> 6) == half) {
#pragma unroll
        for (int a2 = 0; a2 < 4; ++a2)
#pragma unroll
          for (int b2 = 0; b2 < 4; ++b2) {
            const int colb = wn + b2 * 16 + lr;
            const int lrow0 = a2 * 16 + (lane >> 4) * 4;
#pragma unroll
            for (int r = 0; r < 4; ++r)
              gt[(lrow0 + r) * 132 + colb] = acc[a2][b2][r] + biasr[b2];
          }
      }
      __syncthreads();   // gt ready
#pragma unroll
      for (int p = 0; p < 2; ++p) {
        const int lrow = p * 32 + (tid >> 3), q = tid & 7;
        const float* g = &gt[lrow * 132 + q * 16];
        float* cr = creg[half][p];
        ushort4 hv;
#pragma unroll
        for (int k = 0; k < 4; ++k) {
          float4 gk = *(const float4*)(g + k * 4);
          float iv = sigmoidf_(gk.x);
          float fv = sigmoidf_(gk.y);
          float gv = tanhf_(gk.z);
          float ov = sigmoidf_(gk.w);
          float ccn = fv * cr[k] + iv * gv;
          cr[k] = ccn;
          ((unsigned short*)&hv)[k] = f2bf(ov * tanhf_(ccn));
        }
        // coherent (agent) h store — write-through to coherence point, no cache flush
        unsigned long long hvq;
        __builtin_memcpy(&hvq, &hv, 8);
        __hip_atomic_store(
            (unsigned long long*)&hout[(size_t)(bm + half * 64 + lrow) * HID + (bn >> 2) + q * 4],
            hvq, __ATOMIC_RELAXED, __HIP_MEMORY_SCOPE_AGENT);
      }
    }

    // ---- fence-free M-group barrier (16 blocks sharing bm) ----
    asm volatile("s_waitcnt vmcnt(0)" ::: "memory");  // h stores at coherence point
    __syncthreads();
    if (tid == 0)
      smflag = (atomicAdd(&bar[grp * FLAG_STRIDE], 1) == 15) ? 1 : 0;
    __syncthreads();
    if (smflag) {                  // this block releases its group
      if (tid == 0) atomicExch(&bar[grp * FLAG_STRIDE], 0);
      __syncthreads();             // reset complete before any flag publish
      if (tid < 16)
        __hip_atomic_store(&flags[(grp * 16 + tid) * FLAG_STRIDE], t + 1,
                           __ATOMIC_RELAXED, __HIP_MEMORY_SCOPE_AGENT);
    } else if (tid == 0) {
      while (__hip_atomic_load(&flags[bid * FLAG_STRIDE],
                               __ATOMIC_RELAXED, __HIP_MEMORY_SCOPE_AGENT) < t + 1)
        __builtin_amdgcn_s_sleep(1);
    }
    __syncthreads();
  }
}

// ---------------- final GEMV ----------------
__global__ __launch_bounds__(64) void gemv_out(const unsigned short* __restrict__ h,
                                               const float* __restrict__ Wout,
                                               float* __restrict__ out) {
  int b = blockIdx.x;
  int lane = threadIdx.x;
  float s = 0.f;
#pragma unroll
  for (int i = 0; i < 8; ++i) {
    int u = lane + i * 64;
    s += bf2f(h[(size_t)b * HID + u]) * Wout[u];
  }
#pragma unroll
  for (int off = 32; off > 0; off >>= 1) s += __shfl_down(s, off);
  if (lane == 0) out[b] = s;
}

// ---------------- host ----------------
extern "C" void kernel_launch(void* const* d_in, const int* in_sizes, int n_in,
                              void* d_out, int out_size, void* d_ws, size_t ws_size,
                              hipStream_t stream) {
  const float* x     = (const float*)d_in[0];
  const float* gamma = (const float*)d_in[1];
  const float* beta  = (const float*)d_in[2];
  const float* W_in  = (const float*)d_in[3];
  const float* b_in  = (const float*)d_in[4];
  const float* W_ih  = (const float*)d_in[5];
  const float* W_hh  = (const float*)d_in[6];
  const float* b_ih  = (const float*)d_in[7];
  const float* b_hh  = (const float*)d_in[8];
  const float* W_out = (const float*)d_in[9];
  float* out = (float*)d_out;

  // workspace layout (bytes) — R5-proven layout; bar/flags in the old cbuf slot:
  //   0         scale[8192] f32                32768
  //   32768     shift[8192] f32                32768
  //   65536     bias2[2048] f32                 8192
  //   73728     Wg2 bf16 [2048][544]         2228224
  //   2301952   h0  bf16 [2048][512]         2097152
  //   4399104   h1  bf16 [2048][512]         2097152
  //   6496256   bar int[16*16] (1024) + flags int[256*16] (16384)
  //   10690560  xs  bf16 [256][2048][32]    33554432
  //   44244992  BN partials                   524288
  //   44769280  WinB bf16 [8192][8192]     134217728 (optional)
  char* ws = (char*)d_ws;
  float* scale = (float*)(ws + 0);
  float* shift = (float*)(ws + 32768);
  float* bias2 = (float*)(ws + 65536);
  unsigned short* Wg2 = (unsigned short*)(ws + 73728);
  unsigned short* h0  = (unsigned short*)(ws + 2301952);
  unsigned short* h1  = (unsigned short*)(ws + 4399104);
  int* bar   = (int*)(ws + 6496256);
  int* flags = (int*)(ws + 6496256 + 1024);
  unsigned short* xs  = (unsigned short*)(ws + 10690560);
  float* psum = (float*)(ws + 44244992);
  float* psq  = psum + 8 * DIN;
  unsigned short* WinB = (unsigned short*)(ws + 44769280);
  const bool useWinB = ws_size >= (44769280ull + 134217728ull);

  hipMemsetAsync(h0, 0, (size_t)BATCH * HID * 2, stream);
  hipMemsetAsync(bar, 0, 1024 + NBLK * FLAG_STRIDE * 4, stream);  // captured: resets every replay

  bn_partial<<<dim3(32, 8), 256, 0, stream>>>(x, psum, psq);
  bn_finalize<<<32, 256, 0, stream>>>(psum, psq, gamma, beta, scale, shift);
  build_wg2<<<G4, 256, 0, stream>>>(W_hh, W_ih, b_ih, b_hh, Wg2, bias2);

  if (useWinB) {
    cvt_bf16<<<32768, 256, 0, stream>>>(W_in, WinB, (long)DIN * DIN);
    gemm1_old<1><<<dim3(64, 16), 256, 0, stream>>>(x, scale, shift, WinB, b_in, xs);
  } else {
    gemm1_old<0><<<dim3(64, 16), 256, 0, stream>>>(x, scale, shift, W_in, b_in, xs);
  }

  lstm_persist<<<NBLK, 256, 0, stream>>>(xs, Wg2, bias2, h0, h1, bar, flags);

  gemv_out<<<BATCH, 64, 0, stream>>>(h0, W_out, out);
}